// Round 11
// baseline (259.621 us; speedup 1.0000x reference)
//
#include <hip/hip_runtime.h>

// Collapse: out = ((P3@M.T + 16c)@M.T + 4c)@M.T + c,  M = Wzf@Wsum.
//   M2 = NT(M,MT); Y1 = NT(P3,M)+16c; u[j] = 4*dot(M[j,:],c0)+c0[j]
//   out = NT(Y1,M2)+u; P3[t] = sum of tree t's 64 leaves.
// All MFMA operands PRE-SPLIT at production into (hi,lo) bf16 pairs:
//   f = hi + lo exactly as consumed; A*B ~= Ah*Bh + Ah*Bl + Al*Bh.
// MFMA staging: raw ushort8 loads, no per-iter conversion, half the bytes.
// D1 (2432): [0,2048) pool->P3h/l | [2048,2304) vgemm M+MT (split+transposed
//            write from same block) | [2304,2432) c0
// D2 (320):  [0,128) Y1h/l | [128,192) M2h/l | [192,320) u
// D3 (128):  out = NT(Y1,M2)+u (fp32)

#define HD 512
typedef unsigned short u16;
typedef __attribute__((ext_vector_type(8))) short bf16x8;
typedef __attribute__((ext_vector_type(4))) float f32x4;

struct __align__(4) us2 { u16 x, y; };
struct __align__(8) us4 { u16 x, y, z, w; };

__device__ __forceinline__ void split1(float f, u16& h, u16& l) {
    unsigned u = __float_as_uint(f);
    h = (u16)(u >> 16);
    float hi = __uint_as_float(u & 0xFFFF0000u);
    l = (u16)(__float_as_uint(f - hi) >> 16);
}

struct __align__(16) MfmaSmem {        // 20480 B
    u16 Ah[64][40];
    u16 Al[64][40];
    u16 Bh[64][40];
    u16 Bl[64][40];
};

// ---- MFMA NT GEMM on pre-split operands ----
// C[i0:+64, j0:+64] = (Ah+Al)[64x512] @ (Bh+Bl)[64x512].T (+ bscale*bias)
// SPLIT: write (Ch,Cl) bf16 pair; else write fp32 Cf.
template<bool BIAS, bool SPLIT>
__device__ __forceinline__
void mfma_gemm_s(const u16* __restrict__ Ah_, const u16* __restrict__ Al_,
                 const u16* __restrict__ Bh_, const u16* __restrict__ Bl_,
                 u16* __restrict__ Ch, u16* __restrict__ Cl,
                 float* __restrict__ Cf, const float* __restrict__ bias,
                 float bscale, int i0, int j0, MfmaSmem& sm) {
    const int t = threadIdx.x;
    const int sr = t >> 2, sk = (t & 3) << 3;
    const int lane = t & 63, w = t >> 6;
    const int fm = lane & 15, fq = (lane >> 4) << 3;

    const u16* ahp = Ah_ + (size_t)(i0 + sr) * HD + sk;
    const u16* alp = Al_ + (size_t)(i0 + sr) * HD + sk;
    const u16* bhp = Bh_ + (size_t)(j0 + sr) * HD + sk;
    const u16* blp = Bl_ + (size_t)(j0 + sr) * HD + sk;
    bf16x8 rah = *(const bf16x8*)ahp, ral = *(const bf16x8*)alp;
    bf16x8 rbh = *(const bf16x8*)bhp, rbl = *(const bf16x8*)blp;

    f32x4 acc[4] = {};

    for (int it = 0; it < 16; ++it) {
        __syncthreads();
        *(bf16x8*)&sm.Ah[sr][sk] = rah;
        *(bf16x8*)&sm.Al[sr][sk] = ral;
        *(bf16x8*)&sm.Bh[sr][sk] = rbh;
        *(bf16x8*)&sm.Bl[sr][sk] = rbl;
        __syncthreads();

        if (it < 15) {                  // prefetch next k-tile under MFMA
            const int kn = (it + 1) << 5;
            rah = *(const bf16x8*)(ahp + kn);
            ral = *(const bf16x8*)(alp + kn);
            rbh = *(const bf16x8*)(bhp + kn);
            rbl = *(const bf16x8*)(blp + kn);
        }

        bf16x8 ah = *(const bf16x8*)&sm.Ah[(w << 4) + fm][fq];
        bf16x8 al = *(const bf16x8*)&sm.Al[(w << 4) + fm][fq];
        #pragma unroll
        for (int ct = 0; ct < 4; ++ct) {
            bf16x8 bh = *(const bf16x8*)&sm.Bh[(ct << 4) + fm][fq];
            bf16x8 bl = *(const bf16x8*)&sm.Bl[(ct << 4) + fm][fq];
            acc[ct] = __builtin_amdgcn_mfma_f32_16x16x32_bf16(ah, bh, acc[ct], 0, 0, 0);
            acc[ct] = __builtin_amdgcn_mfma_f32_16x16x32_bf16(ah, bl, acc[ct], 0, 0, 0);
            acc[ct] = __builtin_amdgcn_mfma_f32_16x16x32_bf16(al, bh, acc[ct], 0, 0, 0);
        }
    }

    const int orow = i0 + (w << 4) + ((lane >> 4) << 2);
    #pragma unroll
    for (int ct = 0; ct < 4; ++ct) {
        const int col = j0 + (ct << 4) + fm;
        float bv = BIAS ? bscale * bias[col] : 0.f;
        #pragma unroll
        for (int r = 0; r < 4; ++r) {
            float v = acc[ct][r] + bv;
            if (SPLIT) {
                u16 h, l;
                split1(v, h, l);
                Ch[(size_t)(orow + r) * HD + col] = h;
                Cl[(size_t)(orow + r) * HD + col] = l;
            } else {
                Cf[(size_t)(orow + r) * HD + col] = v;
            }
        }
    }
}

// ---- VALU GEMM for M (32x32 tile); writes split M AND split MT (transpose) --
struct VSmem { float As[16][33]; float Bs[16][33]; };

__device__ __forceinline__
void vgemm_both(const float* __restrict__ Wzf, const float* __restrict__ Wz,
                u16* __restrict__ Mh, u16* __restrict__ Ml,
                u16* __restrict__ MTh, u16* __restrict__ MTl,
                int i0, int j0, VSmem& sm) {
    const int t = threadIdx.x;
    const int ti = t >> 4, tj = t & 15;
    float a00 = 0.f, a01 = 0.f, a10 = 0.f, a11 = 0.f;

    for (int k0 = 0; k0 < HD; k0 += 16) {
        __syncthreads();
        {   // As[kk][i] = Wzf[i0+i][k0+kk]
            const int r = t >> 3, kp = (t & 7) << 1;
            float2 v = *(const float2*)&Wzf[(size_t)(i0 + r) * HD + k0 + kp];
            sm.As[kp][r] = v.x; sm.As[kp + 1][r] = v.y;
        }
        {   // Bs[kk][j] = sum_q Wz[q][k0+kk][j0+j]
            const int kk = t >> 4, j2 = (t & 15) << 1;
            const float* src = &Wz[(size_t)(k0 + kk) * HD + j0 + j2];
            float sx = 0.f, sy = 0.f;
            #pragma unroll
            for (int q = 0; q < 4; ++q) {
                float2 v = *(const float2*)(src + q * 262144);
                sx += v.x; sy += v.y;
            }
            sm.Bs[kk][j2] = sx; sm.Bs[kk][j2 + 1] = sy;
        }
        __syncthreads();
        #pragma unroll
        for (int kk = 0; kk < 16; ++kk) {
            float2 xa = *(const float2*)&sm.As[kk][2 * ti];
            float2 yb = *(const float2*)&sm.Bs[kk][2 * tj];
            a00 = fmaf(xa.x, yb.x, a00); a01 = fmaf(xa.x, yb.y, a01);
            a10 = fmaf(xa.y, yb.x, a10); a11 = fmaf(xa.y, yb.y, a11);
        }
    }
    u16 h00, l00, h01, l01, h10, l10, h11, l11;
    split1(a00, h00, l00); split1(a01, h01, l01);
    split1(a10, h10, l10); split1(a11, h11, l11);
    const size_t mo = (size_t)(i0 + 2 * ti) * HD + j0 + 2 * tj;
    *(us2*)&Mh[mo]      = us2{h00, h01};
    *(us2*)&Ml[mo]      = us2{l00, l01};
    *(us2*)&Mh[mo + HD] = us2{h10, h11};
    *(us2*)&Ml[mo + HD] = us2{l10, l11};
    const size_t to = (size_t)(j0 + 2 * tj) * HD + i0 + 2 * ti;
    *(us2*)&MTh[to]      = us2{h00, h10};
    *(us2*)&MTl[to]      = us2{l00, l10};
    *(us2*)&MTh[to + HD] = us2{h01, h11};
    *(us2*)&MTl[to + HD] = us2{l01, l11};
}

// ---- D1: [0,2048) pool | [2048,2304) vgemm M+MT | [2304,2432) c0 ----
union D1Smem { VSmem v; float4 red[192]; };

__global__ __launch_bounds__(256) void kD1(
        const float* __restrict__ x, const float* __restrict__ Wz,
        const float* __restrict__ bz, const float* __restrict__ Wzf,
        const float* __restrict__ bzf,
        u16* __restrict__ P3h, u16* __restrict__ P3l,
        u16* __restrict__ Mh, u16* __restrict__ Ml,
        u16* __restrict__ MTh, u16* __restrict__ MTl,
        float* __restrict__ c0) {
    __shared__ D1Smem sm;
    const int b = blockIdx.x, t = threadIdx.x;
    if (b < 2048) {
        // pool: block = (tree, col-half); wave = row quarter (R9/R10-proven)
        const int tree = b >> 1, cbase = (b & 1) << 6;
        const int c = t & 63, sub = t >> 6;
        const float4* xp = (const float4*)x + (size_t)tree * 8192
                         + (sub << 4) * 128 + cbase + c;
        float4 acc = make_float4(0.f, 0.f, 0.f, 0.f);
        #pragma unroll
        for (int g = 0; g < 2; ++g) {
            float4 v[8];
            #pragma unroll
            for (int i = 0; i < 8; ++i) v[i] = xp[(size_t)(g * 8 + i) * 128];
            #pragma unroll
            for (int i = 0; i < 8; ++i) {
                acc.x += v[i].x; acc.y += v[i].y; acc.z += v[i].z; acc.w += v[i].w;
            }
        }
        if (sub) sm.red[((sub - 1) << 6) + c] = acc;
        __syncthreads();
        if (!sub) {
            float4 r0 = sm.red[c], r1 = sm.red[64 + c], r2 = sm.red[128 + c];
            acc.x += (r0.x + r1.x) + r2.x;
            acc.y += (r0.y + r1.y) + r2.y;
            acc.z += (r0.z + r1.z) + r2.z;
            acc.w += (r0.w + r1.w) + r2.w;
            float vals[4] = {acc.x, acc.y, acc.z, acc.w};
            u16 hh[4], ll[4];
            #pragma unroll
            for (int i = 0; i < 4; ++i) split1(vals[i], hh[i], ll[i]);
            const size_t po = (size_t)tree * HD + ((cbase + c) << 2);
            *(us4*)&P3h[po] = us4{hh[0], hh[1], hh[2], hh[3]};
            *(us4*)&P3l[po] = us4{ll[0], ll[1], ll[2], ll[3]};
        }
    } else if (b < 2304) {
        const int bb = b - 2048;
        vgemm_both(Wzf, Wz, Mh, Ml, MTh, MTl,
                   (bb >> 4) << 5, (bb & 15) << 5, sm.v);
    } else {
        // c0[j] = 4*(dot(bsum, Wzf[j,:]) + bzf[j]); one j per wave
        const int lane = t & 63, w = t >> 6, hb = lane << 3;
        const int j = (b - 2304) * 4 + w;
        float4 s0 = *(const float4*)&bz[hb];
        float4 s1 = *(const float4*)&bz[hb + 4];
        #pragma unroll
        for (int q = 1; q < 4; ++q) {
            float4 t0 = *(const float4*)&bz[q * HD + hb];
            float4 t1 = *(const float4*)&bz[q * HD + hb + 4];
            s0.x += t0.x; s0.y += t0.y; s0.z += t0.z; s0.w += t0.w;
            s1.x += t1.x; s1.y += t1.y; s1.z += t1.z; s1.w += t1.w;
        }
        const float4* wr = (const float4*)&Wzf[(size_t)j * HD + hb];
        float4 w0 = wr[0], w1 = wr[1];
        float p = w0.x * s0.x + w0.y * s0.y + w0.z * s0.z + w0.w * s0.w
                + w1.x * s1.x + w1.y * s1.y + w1.z * s1.z + w1.w * s1.w;
        #pragma unroll
        for (int off = 32; off > 0; off >>= 1) p += __shfl_down(p, off);
        if (lane == 0) c0[j] = 4.f * (p + bzf[j]);
    }
}

// ---- D2: [0,128) Y1 | [128,192) M2 | [192,320) u ----
__global__ __launch_bounds__(256) void kD2(
        const u16* __restrict__ P3h, const u16* __restrict__ P3l,
        const u16* __restrict__ Mh, const u16* __restrict__ Ml,
        const u16* __restrict__ MTh, const u16* __restrict__ MTl,
        const float* __restrict__ c0,
        u16* __restrict__ Y1h, u16* __restrict__ Y1l,
        u16* __restrict__ M2h, u16* __restrict__ M2l,
        float* __restrict__ u) {
    __shared__ MfmaSmem sm;
    const int b = blockIdx.x, t = threadIdx.x;
    if (b < 128) {
        mfma_gemm_s<true, true>(P3h, P3l, Mh, Ml, Y1h, Y1l, nullptr,
                                c0, 16.f, (b >> 3) << 6, (b & 7) << 6, sm);
    } else if (b < 192) {
        const int bb = b - 128;
        mfma_gemm_s<false, true>(Mh, Ml, MTh, MTl, M2h, M2l, nullptr,
                                 nullptr, 0.f, (bb >> 3) << 6, (bb & 7) << 6, sm);
    } else {
        // u[j] = 4*dot(M[j,:], c0) + c0[j], M reconstructed from split
        const int lane = t & 63, w = t >> 6, hb = lane << 3;
        const int j = (b - 192) * 4 + w;
        bf16x8 mh = *(const bf16x8*)&Mh[(size_t)j * HD + hb];
        bf16x8 ml = *(const bf16x8*)&Ml[(size_t)j * HD + hb];
        const float4* cr = (const float4*)&c0[hb];
        float4 q0 = cr[0], q1 = cr[1];
        float cv[8] = {q0.x, q0.y, q0.z, q0.w, q1.x, q1.y, q1.z, q1.w};
        float p = 0.f;
        #pragma unroll
        for (int i = 0; i < 8; ++i) {
            float f = __uint_as_float(((unsigned)(u16)mh[i]) << 16)
                    + __uint_as_float(((unsigned)(u16)ml[i]) << 16);
            p = fmaf(f, cv[i], p);
        }
        #pragma unroll
        for (int off = 32; off > 0; off >>= 1) p += __shfl_down(p, off);
        if (lane == 0) u[j] = 4.f * p + c0[j];
    }
}

// ---- D3: out = NT(Y1, M2) + u ----
__global__ __launch_bounds__(256) void kD3(
        const u16* __restrict__ Y1h, const u16* __restrict__ Y1l,
        const u16* __restrict__ M2h, const u16* __restrict__ M2l,
        const float* __restrict__ u, float* __restrict__ out) {
    __shared__ MfmaSmem sm;
    const int b = blockIdx.x;
    mfma_gemm_s<true, false>(Y1h, Y1l, M2h, M2l, nullptr, nullptr, out,
                             u, 1.f, (b >> 3) << 6, (b & 7) << 6, sm);
}

extern "C" void kernel_launch(void* const* d_in, const int* in_sizes, int n_in,
                              void* d_out, int out_size, void* d_ws, size_t ws_size,
                              hipStream_t stream) {
    const float* x   = (const float*)d_in[0];
    const float* Wz  = (const float*)d_in[1];
    const float* bz  = (const float*)d_in[2];
    const float* Wzf = (const float*)d_in[3];
    const float* bzf = (const float*)d_in[4];
    float* out = (float*)d_out;

    char* base = (char*)d_ws;
    u16* P3h = (u16*)(base);                    // 1 MB  (1024x512)
    u16* P3l = (u16*)(base + (1 << 20));        // 1 MB
    u16* Y1h = (u16*)(base + (2 << 20));        // 1 MB
    u16* Y1l = (u16*)(base + (3 << 20));        // 1 MB
    u16* Mh  = (u16*)(base + (4 << 20));        // 512 KB (512x512)
    u16* Ml  = (u16*)(base + (4 << 20) + (512 << 10));
    u16* MTh = (u16*)(base + (5 << 20));
    u16* MTl = (u16*)(base + (5 << 20) + (512 << 10));
    u16* M2h = (u16*)(base + (6 << 20));
    u16* M2l = (u16*)(base + (6 << 20) + (512 << 10));
    float* c0 = (float*)(base + (7 << 20));     // 2 KB
    float* u  = (float*)(base + (7 << 20) + 2048);

    hipLaunchKernelGGL(kD1, dim3(2432), dim3(256), 0, stream,
                       x, Wz, bz, Wzf, bzf, P3h, P3l, Mh, Ml, MTh, MTl, c0);
    hipLaunchKernelGGL(kD2, dim3(320), dim3(256), 0, stream,
                       P3h, P3l, Mh, Ml, MTh, MTl, c0, Y1h, Y1l, M2h, M2l, u);
    hipLaunchKernelGGL(kD3, dim3(128), dim3(256), 0, stream,
                       Y1h, Y1l, M2h, M2l, u, out);
}